// Round 1
// baseline (2922.230 us; speedup 1.0000x reference)
//
#include <hip/hip_runtime.h>
#include <hip/hip_bf16.h>
#include <math.h>

// Problem constants (from reference)
#define N_ATOMS   50000
#define N_EDGES   800000
#define NODE_DIM  64
#define KDIM      192          // FULL_DIM = 2*64 + 64
#define BN_EPS    1e-5f

#define EDGES_PER_BLOCK 32
#define EPT             8      // edges per thread (4 edge-groups of 8)
#define NBLOCKS         (N_EDGES / EDGES_PER_BLOCK)   // 25000
#define STAT_SLOTS      64

// ---------------------------------------------------------------------------
// Pass 1: gather z into LDS, dual GEMM (core+filter), accumulate column
// sum / sumsq into hierarchical stat slots.
// Thread map: j = t&63 (output column), eg = t>>6 (edge group of 8 edges).
// A wave has uniform eg -> LDS z reads are broadcast (conflict-free).
// ---------------------------------------------------------------------------
__global__ __launch_bounds__(256) void gemm_stats(
    const float* __restrict__ atom, const float* __restrict__ edgef,
    const float* __restrict__ Wc,   const float* __restrict__ Wf,
    const float* __restrict__ bc,   const float* __restrict__ bf,
    const int*   __restrict__ eidx, float* __restrict__ stat_partial)
{
    __shared__ __align__(16) float zl[EDGES_PER_BLOCK * KDIM]; // 24 KB
    const int t = threadIdx.x;
    const int block_e0 = blockIdx.x * EDGES_PER_BLOCK;
    const int wave = t >> 6, lane = t & 63;

    // gather: 96 segments (32 edges x 3) of 64 contiguous floats
    for (int s = wave; s < EDGES_PER_BLOCK * 3; s += 4) {
        int e = s / 3, seg = s - 3 * e;
        int ge = block_e0 + e;
        const float* srcp;
        if (seg == 0)      srcp = atom  + (size_t)eidx[2 * ge + 1] * 64; // dst
        else if (seg == 1) srcp = atom  + (size_t)eidx[2 * ge + 0] * 64; // src
        else               srcp = edgef + (size_t)ge * 64;
        zl[e * KDIM + seg * 64 + lane] = srcp[lane];
    }
    __syncthreads();

    const int j = t & 63, eg = t >> 6;
    const float* zbase = zl + eg * EPT * KDIM;

    float accc[EPT], accf[EPT];
    const float bcj = bc[j], bfj = bf[j];
#pragma unroll
    for (int i = 0; i < EPT; i++) { accc[i] = bcj; accf[i] = bfj; }

    const float4* wcrow = (const float4*)(Wc + j * KDIM);
    const float4* wfrow = (const float4*)(Wf + j * KDIM);
    for (int k4 = 0; k4 < KDIM / 4; k4++) {
        float4 wc = wcrow[k4];
        float4 wf = wfrow[k4];
#pragma unroll
        for (int i = 0; i < EPT; i++) {
            float4 z = *(const float4*)(zbase + i * KDIM + k4 * 4);
            accc[i] = fmaf(z.x, wc.x, accc[i]);
            accc[i] = fmaf(z.y, wc.y, accc[i]);
            accc[i] = fmaf(z.z, wc.z, accc[i]);
            accc[i] = fmaf(z.w, wc.w, accc[i]);
            accf[i] = fmaf(z.x, wf.x, accf[i]);
            accf[i] = fmaf(z.y, wf.y, accf[i]);
            accf[i] = fmaf(z.z, wf.z, accf[i]);
            accf[i] = fmaf(z.w, wf.w, accf[i]);
        }
    }

    // per-thread partial stats over its 8 edges
    float sc = 0.f, qc = 0.f, sf = 0.f, qf = 0.f;
#pragma unroll
    for (int i = 0; i < EPT; i++) {
        sc += accc[i]; qc += accc[i] * accc[i];
        sf += accf[i]; qf += accf[i] * accf[i];
    }

    // reduce across the 4 edge-groups sharing each j
    __shared__ float red[4][256];
    red[0][t] = sc; red[1][t] = qc; red[2][t] = sf; red[3][t] = qf;
    __syncthreads();
    if (eg == 0) {
        float s0 = 0.f, s1 = 0.f, s2 = 0.f, s3 = 0.f;
#pragma unroll
        for (int g = 0; g < 4; g++) {
            s0 += red[0][g * 64 + j]; s1 += red[1][g * 64 + j];
            s2 += red[2][g * 64 + j]; s3 += red[3][g * 64 + j];
        }
        float* slot = stat_partial + (size_t)(blockIdx.x & (STAT_SLOTS - 1)) * 256;
        atomicAdd(slot + j,        s0);   // sum core
        atomicAdd(slot + 64 + j,   s1);   // sumsq core
        atomicAdd(slot + 128 + j,  s2);   // sum filter
        atomicAdd(slot + 192 + j,  s3);   // sumsq filter
    }
}

// ---------------------------------------------------------------------------
// Pass 2: fold BN into per-column scale/shift.
// params layout: [0..63]=scale_c [64..127]=scale_f [128..191]=shift_c [192..255]=shift_f
// ---------------------------------------------------------------------------
__global__ void finalize_stats(const float* __restrict__ stat_partial,
                               const float* __restrict__ gc, const float* __restrict__ btc,
                               const float* __restrict__ gf, const float* __restrict__ btf,
                               float* __restrict__ params)
{
    int t = threadIdx.x;            // 0..127
    bool isf = t >= 64;
    int j = t & 63;
    float s = 0.f, q = 0.f;
    for (int slot = 0; slot < STAT_SLOTS; slot++) {
        const float* sp = stat_partial + (size_t)slot * 256 + (isf ? 128 : 0);
        s += sp[j];
        q += sp[64 + j];
    }
    float mean = s / (float)N_EDGES;
    float var  = q / (float)N_EDGES - mean * mean;
    float inv  = rsqrtf(var + BN_EPS);
    float gamma = isf ? gf[j] : btc == nullptr ? 1.f : gc[j];
    float beta  = isf ? btf[j] : btc[j];
    float scale = gamma * inv;
    float shift = beta - mean * scale;
    params[t]       = scale;
    params[128 + t] = shift;
}

// ---------------------------------------------------------------------------
// out = atom_features (vectorized copy)
// ---------------------------------------------------------------------------
__global__ __launch_bounds__(256) void copy_out(const float4* __restrict__ src,
                                                float4* __restrict__ dst)
{
    int i = blockIdx.x * blockDim.x + threadIdx.x;   // 800000 float4
    dst[i] = src[i];
}

// ---------------------------------------------------------------------------
// Pass 3: recompute GEMM, apply BN + softplus/sigmoid, scatter-add to out.
// Wave lanes share the edge -> atomicAdds are 64 consecutive floats (256B).
// ---------------------------------------------------------------------------
__global__ __launch_bounds__(256) void apply_scatter(
    const float* __restrict__ atom, const float* __restrict__ edgef,
    const float* __restrict__ Wc,   const float* __restrict__ Wf,
    const float* __restrict__ bc,   const float* __restrict__ bf,
    const int*   __restrict__ eidx, const float* __restrict__ params,
    float* __restrict__ out)
{
    __shared__ __align__(16) float zl[EDGES_PER_BLOCK * KDIM];
    const int t = threadIdx.x;
    const int block_e0 = blockIdx.x * EDGES_PER_BLOCK;
    const int wave = t >> 6, lane = t & 63;

    for (int s = wave; s < EDGES_PER_BLOCK * 3; s += 4) {
        int e = s / 3, seg = s - 3 * e;
        int ge = block_e0 + e;
        const float* srcp;
        if (seg == 0)      srcp = atom  + (size_t)eidx[2 * ge + 1] * 64;
        else if (seg == 1) srcp = atom  + (size_t)eidx[2 * ge + 0] * 64;
        else               srcp = edgef + (size_t)ge * 64;
        zl[e * KDIM + seg * 64 + lane] = srcp[lane];
    }
    __syncthreads();

    const int j = t & 63, eg = t >> 6;
    const float* zbase = zl + eg * EPT * KDIM;

    float accc[EPT], accf[EPT];
    const float bcj = bc[j], bfj = bf[j];
#pragma unroll
    for (int i = 0; i < EPT; i++) { accc[i] = bcj; accf[i] = bfj; }

    const float4* wcrow = (const float4*)(Wc + j * KDIM);
    const float4* wfrow = (const float4*)(Wf + j * KDIM);
    for (int k4 = 0; k4 < KDIM / 4; k4++) {
        float4 wc = wcrow[k4];
        float4 wf = wfrow[k4];
#pragma unroll
        for (int i = 0; i < EPT; i++) {
            float4 z = *(const float4*)(zbase + i * KDIM + k4 * 4);
            accc[i] = fmaf(z.x, wc.x, accc[i]);
            accc[i] = fmaf(z.y, wc.y, accc[i]);
            accc[i] = fmaf(z.z, wc.z, accc[i]);
            accc[i] = fmaf(z.w, wc.w, accc[i]);
            accf[i] = fmaf(z.x, wf.x, accf[i]);
            accf[i] = fmaf(z.y, wf.y, accf[i]);
            accf[i] = fmaf(z.z, wf.z, accf[i]);
            accf[i] = fmaf(z.w, wf.w, accf[i]);
        }
    }

    const float scale_c = params[j],      shift_c = params[128 + j];
    const float scale_f = params[64 + j], shift_f = params[192 + j];

#pragma unroll
    for (int i = 0; i < EPT; i++) {
        float pc = fmaf(accc[i], scale_c, shift_c);
        float pf = fmaf(accf[i], scale_f, shift_f);
        // stable softplus: max(x,0) + log1p(exp(-|x|))
        float sp = fmaxf(pc, 0.f) + log1pf(expf(-fabsf(pc)));
        float sg = 1.f / (1.f + expf(-pf));
        float msg = sp * sg;
        int ge = block_e0 + eg * EPT + i;
        int d = eidx[2 * ge + 1];
        atomicAdd(out + (size_t)d * 64 + j, msg);
    }
}

// ---------------------------------------------------------------------------
extern "C" void kernel_launch(void* const* d_in, const int* in_sizes, int n_in,
                              void* d_out, int out_size, void* d_ws, size_t ws_size,
                              hipStream_t stream)
{
    const float* atom  = (const float*)d_in[0];
    const float* edgef = (const float*)d_in[1];
    const float* Wf    = (const float*)d_in[2];
    const float* bf    = (const float*)d_in[3];
    const float* gf    = (const float*)d_in[4];
    const float* btf   = (const float*)d_in[5];
    const float* Wc    = (const float*)d_in[6];
    const float* bc    = (const float*)d_in[7];
    const float* gc    = (const float*)d_in[8];
    const float* btc   = (const float*)d_in[9];
    const int*   eidx  = (const int*)d_in[10];
    float* out = (float*)d_out;

    float* stat_partial = (float*)d_ws;                 // 64 slots x 256 f32
    float* params = stat_partial + STAT_SLOTS * 256;    // 256 f32

    hipMemsetAsync(d_ws, 0, STAT_SLOTS * 256 * sizeof(float), stream);

    gemm_stats<<<NBLOCKS, 256, 0, stream>>>(atom, edgef, Wc, Wf, bc, bf, eidx,
                                            stat_partial);
    finalize_stats<<<1, 128, 0, stream>>>(stat_partial, gc, btc, gf, btf, params);
    copy_out<<<(N_ATOMS * NODE_DIM / 4) / 256, 256, 0, stream>>>(
        (const float4*)atom, (float4*)out);
    apply_scatter<<<NBLOCKS, 256, 0, stream>>>(atom, edgef, Wc, Wf, bc, bf, eidx,
                                               params, out);
}

// Round 2
// 750.810 us; speedup vs baseline: 3.8921x; 3.8921x over previous
//
#include <hip/hip_runtime.h>
#include <hip/hip_bf16.h>
#include <math.h>

// Problem constants
#define N_ATOMS   50000
#define N_EDGES   800000
#define KDIM      192
#define BN_EPS    1e-5f

#define TILE_E          64
#define NTILES          (N_EDGES / TILE_E)          // 12500
#define TILES_PER_BLOCK 10
#define GRID_BLOCKS     (NTILES / TILES_PER_BLOCK) // 1250
#define STAT_SLOTS      32
#define ZSTRIDE         200   // bf16 elems per z row: 192 + 8 pad (keeps 16B align)

typedef __attribute__((ext_vector_type(8))) __bf16 bf16x8;
typedef __attribute__((ext_vector_type(4))) float  f32x4;

__device__ __forceinline__ ushort f2bf(float f) {
    union { float f; unsigned u; } v; v.f = f;
    unsigned u = v.u;
    return (ushort)((u + 0x7FFFu + ((u >> 16) & 1u)) >> 16);
}

// ---------------------------------------------------------------------------
// Gather one 64-edge tile of z = [atom[dst] | atom[src] | edge_feat] into LDS
// as bf16, padded row stride ZSTRIDE. Seg-major task order -> wave-uniform seg.
// ---------------------------------------------------------------------------
__device__ __forceinline__ void gather_tile(
    const float* __restrict__ atom, const float* __restrict__ edgef,
    const int* __restrict__ eidx, int tilebase,
    ushort* zl, int* dstl, int tid, bool want_dst)
{
    if (want_dst && tid < TILE_E) dstl[tid] = eidx[2 * (tilebase + tid) + 1];
#pragma unroll
    for (int it = 0; it < 12; ++it) {
        int id  = it * 256 + tid;       // 0..3071
        int seg = id >> 10;             // 0..2 (wave-uniform per it)
        int rem = id & 1023;
        int e   = rem >> 4;             // 0..63
        int f4  = rem & 15;             // 0..15
        int ge  = tilebase + e;
        const float* srcp;
        if (seg == 0)      srcp = atom  + (size_t)eidx[2 * ge + 1] * 64; // dst
        else if (seg == 1) srcp = atom  + (size_t)eidx[2 * ge + 0] * 64; // src
        else               srcp = edgef + (size_t)ge * 64;
        float4 v = *(const float4*)(srcp + f4 * 4);
        ushort4 b;
        b.x = f2bf(v.x); b.y = f2bf(v.y); b.z = f2bf(v.z); b.w = f2bf(v.w);
        *(ushort4*)&zl[e * ZSTRIDE + seg * 64 + f4 * 4] = b;
    }
}

// ---------------------------------------------------------------------------
// Pass 1: MFMA dual-GEMM, accumulate per-column sum/sumsq (bias dropped: it
// cancels under BatchNorm's mean subtraction).
// Wave w: colhalf ch=w>>1 (32 cols), rowpair rp=w&1 (32 of 64 edges), BOTH mats.
// ---------------------------------------------------------------------------
__global__ __launch_bounds__(256) void gemm_stats_mfma(
    const float* __restrict__ atom, const float* __restrict__ edgef,
    const ushort* __restrict__ Wb, const int* __restrict__ eidx,
    float* __restrict__ stat_partial)
{
    __shared__ __align__(16) ushort zl[TILE_E * ZSTRIDE];
    __shared__ int dstl[TILE_E];
    const int tid  = threadIdx.x;
    const int wave = tid >> 6, lane = tid & 63;
    const int ch = wave >> 1, rp = wave & 1;
    const int row = lane & 15, quad = lane >> 4;

    // hoisted B fragments: [mat][coltile][kstep]
    bf16x8 bfr[2][2][6];
#pragma unroll
    for (int m = 0; m < 2; ++m)
#pragma unroll
        for (int nt = 0; nt < 2; ++nt)
#pragma unroll
            for (int ks = 0; ks < 6; ++ks)
                bfr[m][nt][ks] = *(const bf16x8*)&Wb[
                    (size_t)(m * 64 + ch * 32 + nt * 16 + row) * KDIM + ks * 32 + quad * 8];

    float s[2][2] = {{0.f, 0.f}, {0.f, 0.f}};
    float q[2][2] = {{0.f, 0.f}, {0.f, 0.f}};

    const int t0 = blockIdx.x * TILES_PER_BLOCK;
    for (int tile = t0; tile < t0 + TILES_PER_BLOCK; ++tile) {
        __syncthreads();
        gather_tile(atom, edgef, eidx, tile * TILE_E, zl, dstl, tid, false);
        __syncthreads();
#pragma unroll
        for (int ett = 0; ett < 2; ++ett) {
            const ushort* zb = zl + ((2 * rp + ett) * 16 + row) * ZSTRIDE;
            bf16x8 a[6];
#pragma unroll
            for (int ks = 0; ks < 6; ++ks)
                a[ks] = *(const bf16x8*)&zb[ks * 32 + quad * 8];
            f32x4 acc[2][2];
#pragma unroll
            for (int m = 0; m < 2; ++m)
#pragma unroll
                for (int nt = 0; nt < 2; ++nt)
                    acc[m][nt] = (f32x4){0.f, 0.f, 0.f, 0.f};
#pragma unroll
            for (int ks = 0; ks < 6; ++ks)
#pragma unroll
                for (int m = 0; m < 2; ++m)
#pragma unroll
                    for (int nt = 0; nt < 2; ++nt)
                        acc[m][nt] = __builtin_amdgcn_mfma_f32_16x16x32_bf16(
                            a[ks], bfr[m][nt][ks], acc[m][nt], 0, 0, 0);
#pragma unroll
            for (int m = 0; m < 2; ++m)
#pragma unroll
                for (int nt = 0; nt < 2; ++nt)
#pragma unroll
                    for (int r = 0; r < 4; ++r) {
                        float v = acc[m][nt][r];
                        s[m][nt] += v; q[m][nt] += v * v;
                    }
        }
    }

    float* slot = stat_partial + (size_t)(blockIdx.x & (STAT_SLOTS - 1)) * 256;
#pragma unroll
    for (int m = 0; m < 2; ++m)
#pragma unroll
        for (int nt = 0; nt < 2; ++nt) {
            float sv = s[m][nt], qv = q[m][nt];
            sv += __shfl_xor(sv, 16, 64); sv += __shfl_xor(sv, 32, 64);
            qv += __shfl_xor(qv, 16, 64); qv += __shfl_xor(qv, 32, 64);
            if (lane < 16) {
                int c = ch * 32 + nt * 16 + lane;
                atomicAdd(slot + m * 128 + c, sv);        // sum
                atomicAdd(slot + m * 128 + 64 + c, qv);   // sumsq
            }
        }
}

// ---------------------------------------------------------------------------
// Fold BN into per-column scale/shift.
// params: [0..63]=scale_c [64..127]=scale_f [128..191]=shift_c [192..255]=shift_f
// ---------------------------------------------------------------------------
__global__ void finalize_stats(const float* __restrict__ stat_partial,
                               const float* __restrict__ gc, const float* __restrict__ btc,
                               const float* __restrict__ gf, const float* __restrict__ btf,
                               float* __restrict__ params)
{
    int t = threadIdx.x;            // 0..127
    bool isf = t >= 64;
    int j = t & 63;
    float s = 0.f, q = 0.f;
    for (int slot = 0; slot < STAT_SLOTS; slot++) {
        const float* sp = stat_partial + (size_t)slot * 256 + (isf ? 128 : 0);
        s += sp[j];
        q += sp[64 + j];
    }
    float mean = s / (float)N_EDGES;
    float var  = q / (float)N_EDGES - mean * mean;
    float inv  = rsqrtf(var + BN_EPS);
    float gamma = isf ? gf[j] : gc[j];
    float beta  = isf ? btf[j] : btc[j];
    float scale = gamma * inv;
    float shift = beta - mean * scale;
    params[t]       = scale;
    params[128 + t] = shift;
}

// ---------------------------------------------------------------------------
__global__ __launch_bounds__(256) void copy_out(const float4* __restrict__ src,
                                                float4* __restrict__ dst)
{
    int i = blockIdx.x * blockDim.x + threadIdx.x;
    dst[i] = src[i];
}

// fp32 -> bf16 weight conversion (m=0: core, m=1: filter), 24576 elems
__global__ __launch_bounds__(256) void convert_weights(
    const float* __restrict__ Wc, const float* __restrict__ Wf,
    ushort* __restrict__ Wb)
{
    int i = blockIdx.x * 256 + threadIdx.x;
    float v = (i < 64 * KDIM) ? Wc[i] : Wf[i - 64 * KDIM];
    Wb[i] = f2bf(v);
}

// ---------------------------------------------------------------------------
// Pass 3: recompute MFMA GEMM, BN + sigmoid*softplus, atomic scatter to out.
// ---------------------------------------------------------------------------
__global__ __launch_bounds__(256) void apply_scatter_mfma(
    const float* __restrict__ atom, const float* __restrict__ edgef,
    const ushort* __restrict__ Wb, const int* __restrict__ eidx,
    const float* __restrict__ params, float* __restrict__ out)
{
    __shared__ __align__(16) ushort zl[TILE_E * ZSTRIDE];
    __shared__ int dstl[TILE_E];
    const int tid  = threadIdx.x;
    const int wave = tid >> 6, lane = tid & 63;
    const int ch = wave >> 1, rp = wave & 1;
    const int row = lane & 15, quad = lane >> 4;

    bf16x8 bfr[2][2][6];
#pragma unroll
    for (int m = 0; m < 2; ++m)
#pragma unroll
        for (int nt = 0; nt < 2; ++nt)
#pragma unroll
            for (int ks = 0; ks < 6; ++ks)
                bfr[m][nt][ks] = *(const bf16x8*)&Wb[
                    (size_t)(m * 64 + ch * 32 + nt * 16 + row) * KDIM + ks * 32 + quad * 8];

    float scc[2], shc[2], scf[2], shf[2];
#pragma unroll
    for (int nt = 0; nt < 2; ++nt) {
        int c = ch * 32 + nt * 16 + row;
        scc[nt] = params[c];        shc[nt] = params[128 + c];
        scf[nt] = params[64 + c];   shf[nt] = params[192 + c];
    }

    const int t0 = blockIdx.x * TILES_PER_BLOCK;
    for (int tile = t0; tile < t0 + TILES_PER_BLOCK; ++tile) {
        __syncthreads();
        gather_tile(atom, edgef, eidx, tile * TILE_E, zl, dstl, tid, true);
        __syncthreads();
#pragma unroll
        for (int ett = 0; ett < 2; ++ett) {
            const ushort* zb = zl + ((2 * rp + ett) * 16 + row) * ZSTRIDE;
            bf16x8 a[6];
#pragma unroll
            for (int ks = 0; ks < 6; ++ks)
                a[ks] = *(const bf16x8*)&zb[ks * 32 + quad * 8];
            f32x4 acc[2][2];
#pragma unroll
            for (int m = 0; m < 2; ++m)
#pragma unroll
                for (int nt = 0; nt < 2; ++nt)
                    acc[m][nt] = (f32x4){0.f, 0.f, 0.f, 0.f};
#pragma unroll
            for (int ks = 0; ks < 6; ++ks)
#pragma unroll
                for (int m = 0; m < 2; ++m)
#pragma unroll
                    for (int nt = 0; nt < 2; ++nt)
                        acc[m][nt] = __builtin_amdgcn_mfma_f32_16x16x32_bf16(
                            a[ks], bfr[m][nt][ks], acc[m][nt], 0, 0, 0);

            int ebase = (2 * rp + ett) * 16 + quad * 4;  // local edge idx of reg 0
#pragma unroll
            for (int nt = 0; nt < 2; ++nt) {
                int c = ch * 32 + nt * 16 + row;
#pragma unroll
                for (int r = 0; r < 4; ++r) {
                    float pc = fmaf(acc[0][nt][r], scc[nt], shc[nt]);
                    float pf = fmaf(acc[1][nt][r], scf[nt], shf[nt]);
                    float sp = fmaxf(pc, 0.f) + __logf(1.f + __expf(-fabsf(pc)));
                    float sg = 1.f / (1.f + __expf(-pf));
                    int d = dstl[ebase + r];
                    atomicAdd(out + (size_t)d * 64 + c, sp * sg);
                }
            }
        }
    }
}

// ---------------------------------------------------------------------------
extern "C" void kernel_launch(void* const* d_in, const int* in_sizes, int n_in,
                              void* d_out, int out_size, void* d_ws, size_t ws_size,
                              hipStream_t stream)
{
    const float* atom  = (const float*)d_in[0];
    const float* edgef = (const float*)d_in[1];
    const float* Wf    = (const float*)d_in[2];
    // d_in[3] = b_filter (unused: bias cancels in BN)
    const float* gf    = (const float*)d_in[4];
    const float* btf   = (const float*)d_in[5];
    const float* Wc    = (const float*)d_in[6];
    // d_in[7] = b_core (unused)
    const float* gc    = (const float*)d_in[8];
    const float* btc   = (const float*)d_in[9];
    const int*   eidx  = (const int*)d_in[10];
    float* out = (float*)d_out;

    float*  stat_partial = (float*)d_ws;                       // 32*256 f32
    float*  params       = stat_partial + STAT_SLOTS * 256;    // 256 f32
    ushort* Wb           = (ushort*)(params + 256);            // 2*64*192 bf16

    hipMemsetAsync(d_ws, 0, STAT_SLOTS * 256 * sizeof(float), stream);
    convert_weights<<<(2 * 64 * KDIM) / 256, 256, 0, stream>>>(Wc, Wf, Wb);

    gemm_stats_mfma<<<GRID_BLOCKS, 256, 0, stream>>>(atom, edgef, Wb, eidx,
                                                     stat_partial);
    finalize_stats<<<1, 128, 0, stream>>>(stat_partial, gc, btc, gf, btf, params);
    copy_out<<<(N_ATOMS * 64 / 4) / 256, 256, 0, stream>>>(
        (const float4*)atom, (float4*)out);
    apply_scatter_mfma<<<GRID_BLOCKS, 256, 0, stream>>>(atom, edgef, Wb, eidx,
                                                        params, out);
}

// Round 4
// 568.597 us; speedup vs baseline: 5.1394x; 1.3205x over previous
//
#include <hip/hip_runtime.h>
#include <hip/hip_bf16.h>
#include <math.h>

// Problem constants
#define N_ATOMS   50000
#define N_EDGES   800000
#define KDIM      192
#define BN_EPS    1e-5f

#define TILE_E     64
#define TPB        5                       // tiles per block (pass 1)
#define NTILES     (N_EDGES / TILE_E)      // 12500
#define GRID1      (NTILES / TPB)          // 2500
#define STAT_SLOTS 32
#define ZSTRIDE    200   // bf16 elems per z row (192 + 8 pad, 16B-aligned rows)

typedef __attribute__((ext_vector_type(8))) __bf16 bf16x8;
typedef __attribute__((ext_vector_type(4))) float  f32x4;
typedef __attribute__((ext_vector_type(4))) unsigned short u16x4;

__device__ __forceinline__ ushort f2bf(float f) {
    union { float f; unsigned u; } v; v.f = f;
    unsigned u = v.u;
    return (ushort)((u + 0x7FFFu + ((u >> 16) & 1u)) >> 16);
}
__device__ __forceinline__ float bf2f(unsigned hi16) {
    union { unsigned u; float f; } v; v.u = hi16 << 16; return v.f;
}

// ---------------------------------------------------------------------------
// Gather one 64-edge z-tile into LDS (bf16). eidxl = this tile's 128 indices
// (already in LDS). All 12 global float4 loads are issued as one batch for
// memory-level parallelism; seg is compile-time per unrolled iteration.
// ---------------------------------------------------------------------------
__device__ __forceinline__ void gather_tile(
    const float* __restrict__ atom, const float* __restrict__ edgef,
    const int* eidxl, int tilebase, ushort* zl, int tid)
{
    const int er = tid >> 4, f4 = tid & 15;
    const float* p[12];
#pragma unroll
    for (int it = 0; it < 12; ++it) {
        const int seg = it >> 2;
        const int e   = (it & 3) * 16 + er;
        const float* srcp;
        if (seg == 0)      srcp = atom  + (size_t)eidxl[2 * e + 1] * 64; // dst
        else if (seg == 1) srcp = atom  + (size_t)eidxl[2 * e] * 64;     // src
        else               srcp = edgef + (size_t)(tilebase + e) * 64;
        p[it] = srcp + f4 * 4;
    }
    f32x4 v[12];
#pragma unroll
    for (int it = 0; it < 12; ++it) {
        if ((it >> 2) == 2) v[it] = __builtin_nontemporal_load((const f32x4*)p[it]);
        else                v[it] = *(const f32x4*)p[it];
    }
#pragma unroll
    for (int it = 0; it < 12; ++it) {
        const int seg = it >> 2;
        const int e   = (it & 3) * 16 + er;
        u16x4 b;
        b.x = f2bf(v[it].x); b.y = f2bf(v[it].y);
        b.z = f2bf(v[it].z); b.w = f2bf(v[it].w);
        *(u16x4*)&zl[e * ZSTRIDE + seg * 64 + f4 * 4] = b;
    }
}

// ---------------------------------------------------------------------------
// Pass 1: gather + MFMA dual-GEMM + column sum/sumsq; optionally store packed
// bf16 pre-activations (core|filter<<16) to ws_pre for the streaming pass 3.
// Bias dropped (cancels under BN mean subtraction).
// ---------------------------------------------------------------------------
__global__ __launch_bounds__(256) void gemm_stats_store(
    const float* __restrict__ atom, const float* __restrict__ edgef,
    const ushort* __restrict__ Wb, const int* __restrict__ eidx,
    float* __restrict__ stat_partial, unsigned* __restrict__ ws_pre,
    int do_store)
{
    __shared__ __align__(16) ushort zl[TILE_E * ZSTRIDE];
    __shared__ int eidxl[TPB * 128];
    const int tid  = threadIdx.x;
    const int lane = tid & 63, wave = tid >> 6;
    const int ch = wave >> 1, rp = wave & 1;
    const int row = lane & 15, quad = lane >> 4;

    const int base2 = blockIdx.x * TPB * 128;
    for (int i = tid; i < TPB * 128; i += 256) eidxl[i] = eidx[base2 + i];

    bf16x8 bfr[2][2][6];
#pragma unroll
    for (int m = 0; m < 2; ++m)
#pragma unroll
        for (int nt = 0; nt < 2; ++nt)
#pragma unroll
            for (int ks = 0; ks < 6; ++ks)
                bfr[m][nt][ks] = *(const bf16x8*)&Wb[
                    (size_t)(m * 64 + ch * 32 + nt * 16 + row) * KDIM + ks * 32 + quad * 8];

    float s[2][2] = {{0.f, 0.f}, {0.f, 0.f}};
    float q[2][2] = {{0.f, 0.f}, {0.f, 0.f}};

    const int t0 = blockIdx.x * TPB;
    for (int tt = 0; tt < TPB; ++tt) {
        const int tilebase = (t0 + tt) * TILE_E;
        __syncthreads();
        gather_tile(atom, edgef, eidxl + tt * 128, tilebase, zl, tid);
        __syncthreads();
#pragma unroll
        for (int ett = 0; ett < 2; ++ett) {
            const ushort* zb = zl + ((2 * rp + ett) * 16 + row) * ZSTRIDE;
            bf16x8 a[6];
#pragma unroll
            for (int ks = 0; ks < 6; ++ks)
                a[ks] = *(const bf16x8*)&zb[ks * 32 + quad * 8];
            f32x4 acc[2][2];
#pragma unroll
            for (int m = 0; m < 2; ++m)
#pragma unroll
                for (int nt = 0; nt < 2; ++nt)
                    acc[m][nt] = (f32x4){0.f, 0.f, 0.f, 0.f};
#pragma unroll
            for (int ks = 0; ks < 6; ++ks)
#pragma unroll
                for (int m = 0; m < 2; ++m)
#pragma unroll
                    for (int nt = 0; nt < 2; ++nt)
                        acc[m][nt] = __builtin_amdgcn_mfma_f32_16x16x32_bf16(
                            a[ks], bfr[m][nt][ks], acc[m][nt], 0, 0, 0);
#pragma unroll
            for (int nt = 0; nt < 2; ++nt) {
                const int c = ch * 32 + nt * 16 + row;
#pragma unroll
                for (int r = 0; r < 4; ++r) {
                    float vc = acc[0][nt][r], vf = acc[1][nt][r];
                    s[0][nt] += vc; q[0][nt] += vc * vc;
                    s[1][nt] += vf; q[1][nt] += vf * vf;
                    if (do_store) {
                        const int eloc = (2 * rp + ett) * 16 + quad * 4 + r;
                        unsigned pack = (unsigned)f2bf(vc) | ((unsigned)f2bf(vf) << 16);
                        __builtin_nontemporal_store(pack,
                            ws_pre + (size_t)(tilebase + eloc) * 64 + c);
                    }
                }
            }
        }
    }

    float* slot = stat_partial + (size_t)(blockIdx.x & (STAT_SLOTS - 1)) * 256;
#pragma unroll
    for (int m = 0; m < 2; ++m)
#pragma unroll
        for (int nt = 0; nt < 2; ++nt) {
            float sv = s[m][nt], qv = q[m][nt];
            sv += __shfl_xor(sv, 16, 64); sv += __shfl_xor(sv, 32, 64);
            qv += __shfl_xor(qv, 16, 64); qv += __shfl_xor(qv, 32, 64);
            if (lane < 16) {
                int c = ch * 32 + nt * 16 + lane;
                atomicAdd(slot + m * 128 + c, sv);
                atomicAdd(slot + m * 128 + 64 + c, qv);
            }
        }
}

// ---------------------------------------------------------------------------
// Fold BN into per-column scale/shift.
// params: [0..63]=scale_c [64..127]=scale_f [128..191]=shift_c [192..255]=shift_f
// ---------------------------------------------------------------------------
__global__ void finalize_stats(const float* __restrict__ stat_partial,
                               const float* __restrict__ gc, const float* __restrict__ btc,
                               const float* __restrict__ gf, const float* __restrict__ btf,
                               float* __restrict__ params)
{
    int t = threadIdx.x;            // 0..127
    bool isf = t >= 64;
    int j = t & 63;
    float s = 0.f, q = 0.f;
    for (int slot = 0; slot < STAT_SLOTS; slot++) {
        const float* sp = stat_partial + (size_t)slot * 256 + (isf ? 128 : 0);
        s += sp[j];
        q += sp[64 + j];
    }
    float mean = s / (float)N_EDGES;
    float var  = q / (float)N_EDGES - mean * mean;
    float inv  = rsqrtf(var + BN_EPS);
    float gamma = isf ? gf[j] : gc[j];
    float beta  = isf ? btf[j] : btc[j];
    float scale = gamma * inv;
    float shift = beta - mean * scale;
    params[t]       = scale;
    params[128 + t] = shift;
}

// ---------------------------------------------------------------------------
__global__ __launch_bounds__(256) void copy_out(const f32x4* __restrict__ src,
                                                f32x4* __restrict__ dst)
{
    int i = blockIdx.x * blockDim.x + threadIdx.x;
    dst[i] = src[i];
}

__global__ __launch_bounds__(256) void convert_weights(
    const float* __restrict__ Wc, const float* __restrict__ Wf,
    ushort* __restrict__ Wb)
{
    int i = blockIdx.x * 256 + threadIdx.x;
    float v = (i < 64 * KDIM) ? Wc[i] : Wf[i - 64 * KDIM];
    Wb[i] = f2bf(v);
}

// ---------------------------------------------------------------------------
// Pass 3 (cached path): stream packed pre-acts, BN + sigmoid*softplus,
// coalesced atomic scatter. One wave = 64 cols of 64 consecutive edges.
// ---------------------------------------------------------------------------
__global__ __launch_bounds__(256) void bn_act_scatter(
    const unsigned* __restrict__ ws_pre, const int* __restrict__ eidx,
    const float* __restrict__ params, float* __restrict__ out)
{
    const int lane = threadIdx.x & 63;
    const int gw   = blockIdx.x * 4 + (threadIdx.x >> 6);
    const int e0   = gw * 64;

    const float sc_c = params[lane],      sh_c = params[128 + lane];
    const float sc_f = params[64 + lane], sh_f = params[192 + lane];

    for (int i = 0; i < 64; i += 8) {
        unsigned pv[8]; int dv[8];
#pragma unroll
        for (int k = 0; k < 8; ++k) {
            int e = e0 + i + k;
            pv[k] = __builtin_nontemporal_load(ws_pre + (size_t)e * 64 + lane);
            dv[k] = eidx[2 * e + 1];
        }
#pragma unroll
        for (int k = 0; k < 8; ++k) {
            float pc = fmaf(bf2f(pv[k] & 0xFFFFu), sc_c, sh_c);
            float pf = fmaf(bf2f(pv[k] >> 16),     sc_f, sh_f);
            float sp = fmaxf(pc, 0.f) + __logf(1.f + __expf(-fabsf(pc)));
            float sg = 1.f / (1.f + __expf(-pf));
            atomicAdd(out + (size_t)dv[k] * 64 + lane, sp * sg);
        }
    }
}

// ---------------------------------------------------------------------------
// Fallback pass 3 (ws too small): recompute GEMM then act+scatter.
// ---------------------------------------------------------------------------
__global__ __launch_bounds__(256) void apply_scatter_fb(
    const float* __restrict__ atom, const float* __restrict__ edgef,
    const ushort* __restrict__ Wb, const int* __restrict__ eidx,
    const float* __restrict__ params, float* __restrict__ out)
{
    __shared__ __align__(16) ushort zl[TILE_E * ZSTRIDE];
    __shared__ int eidxl[TPB * 128];
    const int tid  = threadIdx.x;
    const int lane = tid & 63, wave = tid >> 6;
    const int ch = wave >> 1, rp = wave & 1;
    const int row = lane & 15, quad = lane >> 4;

    const int base2 = blockIdx.x * TPB * 128;
    for (int i = tid; i < TPB * 128; i += 256) eidxl[i] = eidx[base2 + i];

    bf16x8 bfr[2][2][6];
#pragma unroll
    for (int m = 0; m < 2; ++m)
#pragma unroll
        for (int nt = 0; nt < 2; ++nt)
#pragma unroll
            for (int ks = 0; ks < 6; ++ks)
                bfr[m][nt][ks] = *(const bf16x8*)&Wb[
                    (size_t)(m * 64 + ch * 32 + nt * 16 + row) * KDIM + ks * 32 + quad * 8];

    float scc[2], shc[2], scf[2], shf[2];
#pragma unroll
    for (int nt = 0; nt < 2; ++nt) {
        int c = ch * 32 + nt * 16 + row;
        scc[nt] = params[c];        shc[nt] = params[128 + c];
        scf[nt] = params[64 + c];   shf[nt] = params[192 + c];
    }

    const int t0 = blockIdx.x * TPB;
    for (int tt = 0; tt < TPB; ++tt) {
        const int tilebase = (t0 + tt) * TILE_E;
        __syncthreads();
        gather_tile(atom, edgef, eidxl + tt * 128, tilebase, zl, tid);
        __syncthreads();
#pragma unroll
        for (int ett = 0; ett < 2; ++ett) {
            const ushort* zb = zl + ((2 * rp + ett) * 16 + row) * ZSTRIDE;
            bf16x8 a[6];
#pragma unroll
            for (int ks = 0; ks < 6; ++ks)
                a[ks] = *(const bf16x8*)&zb[ks * 32 + quad * 8];
            f32x4 acc[2][2];
#pragma unroll
            for (int m = 0; m < 2; ++m)
#pragma unroll
                for (int nt = 0; nt < 2; ++nt)
                    acc[m][nt] = (f32x4){0.f, 0.f, 0.f, 0.f};
#pragma unroll
            for (int ks = 0; ks < 6; ++ks)
#pragma unroll
                for (int m = 0; m < 2; ++m)
#pragma unroll
                    for (int nt = 0; nt < 2; ++nt)
                        acc[m][nt] = __builtin_amdgcn_mfma_f32_16x16x32_bf16(
                            a[ks], bfr[m][nt][ks], acc[m][nt], 0, 0, 0);
#pragma unroll
            for (int nt = 0; nt < 2; ++nt) {
                int c = ch * 32 + nt * 16 + row;
#pragma unroll
                for (int r = 0; r < 4; ++r) {
                    float pc = fmaf(acc[0][nt][r], scc[nt], shc[nt]);
                    float pf = fmaf(acc[1][nt][r], scf[nt], shf[nt]);
                    float sp = fmaxf(pc, 0.f) + __logf(1.f + __expf(-fabsf(pc)));
                    float sg = 1.f / (1.f + __expf(-pf));
                    int eloc = (2 * rp + ett) * 16 + quad * 4 + r;
                    int d = eidxl[tt * 128 + 2 * eloc + 1];
                    atomicAdd(out + (size_t)d * 64 + c, sp * sg);
                }
            }
        }
    }
}

// ---------------------------------------------------------------------------
extern "C" void kernel_launch(void* const* d_in, const int* in_sizes, int n_in,
                              void* d_out, int out_size, void* d_ws, size_t ws_size,
                              hipStream_t stream)
{
    const float* atom  = (const float*)d_in[0];
    const float* edgef = (const float*)d_in[1];
    const float* Wf    = (const float*)d_in[2];
    const float* gf    = (const float*)d_in[4];
    const float* btf   = (const float*)d_in[5];
    const float* Wc    = (const float*)d_in[6];
    const float* gc    = (const float*)d_in[8];
    const float* btc   = (const float*)d_in[9];
    const int*   eidx  = (const int*)d_in[10];
    float* out = (float*)d_out;

    float*    stat_partial = (float*)d_ws;                     // 32*256 f32
    float*    params       = stat_partial + STAT_SLOTS * 256;  // 256 f32
    ushort*   Wb           = (ushort*)(params + 256);          // 24576 bf16
    unsigned* ws_pre       = (unsigned*)(Wb + 2 * 64 * KDIM);  // 800000*64 u32

    const size_t need = (size_t)STAT_SLOTS * 256 * 4 + 256 * 4 +
                        (size_t)2 * 64 * KDIM * 2 + (size_t)N_EDGES * 64 * 4;
    const int cache = (ws_size >= need) ? 1 : 0;

    (void)hipMemsetAsync(d_ws, 0, STAT_SLOTS * 256 * sizeof(float), stream);
    convert_weights<<<(2 * 64 * KDIM) / 256, 256, 0, stream>>>(Wc, Wf, Wb);

    gemm_stats_store<<<GRID1, 256, 0, stream>>>(atom, edgef, Wb, eidx,
                                                stat_partial, ws_pre, cache);
    finalize_stats<<<1, 128, 0, stream>>>(stat_partial, gc, btc, gf, btf, params);
    copy_out<<<(N_ATOMS * 64 / 4) / 256, 256, 0, stream>>>(
        (const f32x4*)atom, (f32x4*)out);
    if (cache)
        bn_act_scatter<<<N_EDGES / (4 * 64), 256, 0, stream>>>(ws_pre, eidx,
                                                               params, out);
    else
        apply_scatter_fb<<<GRID1, 256, 0, stream>>>(atom, edgef, Wb, eidx,
                                                    params, out);
}

// Round 5
// 555.110 us; speedup vs baseline: 5.2642x; 1.0243x over previous
//
#include <hip/hip_runtime.h>
#include <hip/hip_bf16.h>
#include <math.h>

// Problem constants
#define N_ATOMS   50000
#define N_EDGES   800000
#define KDIM      192
#define BN_EPS    1e-5f

#define TILE_E     64
#define TPB        5                       // tiles per block (pass 1)
#define NTILES     (N_EDGES / TILE_E)      // 12500
#define GRID1      (NTILES / TPB)          // 2500
#define STAT_SLOTS 32
#define ZSTRIDE    200   // bf16 elems per z row (192 + 8 pad, 16B-aligned rows)
#define NSCANBLK   ((N_ATOMS + 255) / 256) // 196

typedef __attribute__((ext_vector_type(8))) __bf16 bf16x8;
typedef __attribute__((ext_vector_type(4))) float  f32x4;
typedef __attribute__((ext_vector_type(4))) unsigned short u16x4;

__device__ __forceinline__ ushort f2bf(float f) {
    union { float f; unsigned u; } v; v.f = f;
    unsigned u = v.u;
    return (ushort)((u + 0x7FFFu + ((u >> 16) & 1u)) >> 16);
}
__device__ __forceinline__ float bf2f(unsigned hi16) {
    union { unsigned u; float f; } v; v.u = hi16 << 16; return v.f;
}
// BN + sigmoid*softplus message from packed (core | filter<<16) bf16 pair
__device__ __forceinline__ float msgf(unsigned pv, float sc_c, float sh_c,
                                      float sc_f, float sh_f) {
    float pc = fmaf(bf2f(pv & 0xFFFFu), sc_c, sh_c);
    float pf = fmaf(bf2f(pv >> 16),     sc_f, sh_f);
    float sp = fmaxf(pc, 0.f) + __logf(1.f + __expf(-fabsf(pc)));
    float sg = 1.f / (1.f + __expf(-pf));
    return sp * sg;
}

// ---------------------------------------------------------------------------
// Gather one 64-edge z-tile into LDS (bf16). All 12 global float4 loads issued
// as one batch for memory-level parallelism.
// ---------------------------------------------------------------------------
__device__ __forceinline__ void gather_tile(
    const float* __restrict__ atom, const float* __restrict__ edgef,
    const int* eidxl, int tilebase, ushort* zl, int tid)
{
    const int er = tid >> 4, f4 = tid & 15;
    const float* p[12];
#pragma unroll
    for (int it = 0; it < 12; ++it) {
        const int seg = it >> 2;
        const int e   = (it & 3) * 16 + er;
        const float* srcp;
        if (seg == 0)      srcp = atom  + (size_t)eidxl[2 * e + 1] * 64; // dst
        else if (seg == 1) srcp = atom  + (size_t)eidxl[2 * e] * 64;     // src
        else               srcp = edgef + (size_t)(tilebase + e) * 64;
        p[it] = srcp + f4 * 4;
    }
    f32x4 v[12];
#pragma unroll
    for (int it = 0; it < 12; ++it) {
        if ((it >> 2) == 2) v[it] = __builtin_nontemporal_load((const f32x4*)p[it]);
        else                v[it] = *(const f32x4*)p[it];
    }
#pragma unroll
    for (int it = 0; it < 12; ++it) {
        const int seg = it >> 2;
        const int e   = (it & 3) * 16 + er;
        u16x4 b;
        b.x = f2bf(v[it].x); b.y = f2bf(v[it].y);
        b.z = f2bf(v[it].z); b.w = f2bf(v[it].w);
        *(u16x4*)&zl[e * ZSTRIDE + seg * 64 + f4 * 4] = b;
    }
}

// ---------------------------------------------------------------------------
// Pass 1: gather + MFMA dual-GEMM + column sum/sumsq; store packed bf16
// pre-activations (core | filter<<16) when do_store.
// ---------------------------------------------------------------------------
__global__ __launch_bounds__(256) void gemm_stats_store(
    const float* __restrict__ atom, const float* __restrict__ edgef,
    const ushort* __restrict__ Wb, const int* __restrict__ eidx,
    float* __restrict__ stat_partial, unsigned* __restrict__ ws_pre,
    int do_store)
{
    __shared__ __align__(16) ushort zl[TILE_E * ZSTRIDE];
    __shared__ int eidxl[TPB * 128];
    const int tid  = threadIdx.x;
    const int lane = tid & 63, wave = tid >> 6;
    const int ch = wave >> 1, rp = wave & 1;
    const int row = lane & 15, quad = lane >> 4;

    const int base2 = blockIdx.x * TPB * 128;
    for (int i = tid; i < TPB * 128; i += 256) eidxl[i] = eidx[base2 + i];

    bf16x8 bfr[2][2][6];
#pragma unroll
    for (int m = 0; m < 2; ++m)
#pragma unroll
        for (int nt = 0; nt < 2; ++nt)
#pragma unroll
            for (int ks = 0; ks < 6; ++ks)
                bfr[m][nt][ks] = *(const bf16x8*)&Wb[
                    (size_t)(m * 64 + ch * 32 + nt * 16 + row) * KDIM + ks * 32 + quad * 8];

    float s[2][2] = {{0.f, 0.f}, {0.f, 0.f}};
    float q[2][2] = {{0.f, 0.f}, {0.f, 0.f}};

    const int t0 = blockIdx.x * TPB;
    for (int tt = 0; tt < TPB; ++tt) {
        const int tilebase = (t0 + tt) * TILE_E;
        __syncthreads();
        gather_tile(atom, edgef, eidxl + tt * 128, tilebase, zl, tid);
        __syncthreads();
#pragma unroll
        for (int ett = 0; ett < 2; ++ett) {
            const ushort* zb = zl + ((2 * rp + ett) * 16 + row) * ZSTRIDE;
            bf16x8 a[6];
#pragma unroll
            for (int ks = 0; ks < 6; ++ks)
                a[ks] = *(const bf16x8*)&zb[ks * 32 + quad * 8];
            f32x4 acc[2][2];
#pragma unroll
            for (int m = 0; m < 2; ++m)
#pragma unroll
                for (int nt = 0; nt < 2; ++nt)
                    acc[m][nt] = (f32x4){0.f, 0.f, 0.f, 0.f};
#pragma unroll
            for (int ks = 0; ks < 6; ++ks)
#pragma unroll
                for (int m = 0; m < 2; ++m)
#pragma unroll
                    for (int nt = 0; nt < 2; ++nt)
                        acc[m][nt] = __builtin_amdgcn_mfma_f32_16x16x32_bf16(
                            a[ks], bfr[m][nt][ks], acc[m][nt], 0, 0, 0);
#pragma unroll
            for (int nt = 0; nt < 2; ++nt) {
                const int c = ch * 32 + nt * 16 + row;
#pragma unroll
                for (int r = 0; r < 4; ++r) {
                    float vc = acc[0][nt][r], vf = acc[1][nt][r];
                    s[0][nt] += vc; q[0][nt] += vc * vc;
                    s[1][nt] += vf; q[1][nt] += vf * vf;
                    if (do_store) {
                        const int eloc = (2 * rp + ett) * 16 + quad * 4 + r;
                        unsigned pack = (unsigned)f2bf(vc) | ((unsigned)f2bf(vf) << 16);
                        __builtin_nontemporal_store(pack,
                            ws_pre + (size_t)(tilebase + eloc) * 64 + c);
                    }
                }
            }
        }
    }

    float* slot = stat_partial + (size_t)(blockIdx.x & (STAT_SLOTS - 1)) * 256;
#pragma unroll
    for (int m = 0; m < 2; ++m)
#pragma unroll
        for (int nt = 0; nt < 2; ++nt) {
            float sv = s[m][nt], qv = q[m][nt];
            sv += __shfl_xor(sv, 16, 64); sv += __shfl_xor(sv, 32, 64);
            qv += __shfl_xor(qv, 16, 64); qv += __shfl_xor(qv, 32, 64);
            if (lane < 16) {
                int c = ch * 32 + nt * 16 + lane;
                atomicAdd(slot + m * 128 + c, sv);
                atomicAdd(slot + m * 128 + 64 + c, qv);
            }
        }
}

// ---------------------------------------------------------------------------
// Fold BN into per-column scale/shift.
// params: [0..63]=scale_c [64..127]=scale_f [128..191]=shift_c [192..255]=shift_f
// ---------------------------------------------------------------------------
__global__ void finalize_stats(const float* __restrict__ stat_partial,
                               const float* __restrict__ gc, const float* __restrict__ btc,
                               const float* __restrict__ gf, const float* __restrict__ btf,
                               float* __restrict__ params)
{
    int t = threadIdx.x;            // 0..127
    bool isf = t >= 64;
    int j = t & 63;
    float s = 0.f, q = 0.f;
    for (int slot = 0; slot < STAT_SLOTS; slot++) {
        const float* sp = stat_partial + (size_t)slot * 256 + (isf ? 128 : 0);
        s += sp[j];
        q += sp[64 + j];
    }
    float mean = s / (float)N_EDGES;
    float var  = q / (float)N_EDGES - mean * mean;
    float inv  = rsqrtf(var + BN_EPS);
    float gamma = isf ? gf[j] : gc[j];
    float beta  = isf ? btf[j] : btc[j];
    float scale = gamma * inv;
    float shift = beta - mean * scale;
    params[t]       = scale;
    params[128 + t] = shift;
}

__global__ __launch_bounds__(256) void convert_weights(
    const float* __restrict__ Wc, const float* __restrict__ Wf,
    ushort* __restrict__ Wb)
{
    int i = blockIdx.x * 256 + threadIdx.x;
    float v = (i < 64 * KDIM) ? Wc[i] : Wf[i - 64 * KDIM];
    Wb[i] = f2bf(v);
}

// ---------------------------------------------------------------------------
// CSR build: histogram -> 2-level exclusive scan -> cursors -> fill
// ---------------------------------------------------------------------------
__global__ __launch_bounds__(256) void hist_dst(const int* __restrict__ eidx,
                                                unsigned* __restrict__ counts)
{
    int e = blockIdx.x * 256 + threadIdx.x;          // 3125 blocks
    atomicAdd(&counts[eidx[2 * e + 1]], 1u);
}

__global__ __launch_bounds__(256) void scan_a(const unsigned* __restrict__ counts,
                                              unsigned* __restrict__ row_start,
                                              unsigned* __restrict__ blksum)
{
    __shared__ unsigned sh[256];
    const int tid = threadIdx.x;
    const int i = blockIdx.x * 256 + tid;
    unsigned v = (i < N_ATOMS) ? counts[i] : 0u;
    sh[tid] = v;
    __syncthreads();
    for (int off = 1; off < 256; off <<= 1) {
        unsigned t = (tid >= off) ? sh[tid - off] : 0u;
        __syncthreads();
        sh[tid] += t;
        __syncthreads();
    }
    if (i < N_ATOMS) row_start[i] = sh[tid] - v;     // exclusive
    if (tid == 255) blksum[blockIdx.x] = sh[tid];
}

__global__ void scan_b(unsigned* __restrict__ blksum)   // 1 block
{
    __shared__ unsigned sh[256];
    const int tid = threadIdx.x;
    unsigned v = (tid < NSCANBLK) ? blksum[tid] : 0u;
    sh[tid] = v;
    __syncthreads();
    for (int off = 1; off < 256; off <<= 1) {
        unsigned t = (tid >= off) ? sh[tid - off] : 0u;
        __syncthreads();
        sh[tid] += t;
        __syncthreads();
    }
    if (tid < NSCANBLK) blksum[tid] = sh[tid] - v;   // exclusive
}

__global__ __launch_bounds__(256) void init_cursor(unsigned* __restrict__ row_start,
                                                   const unsigned* __restrict__ blksum,
                                                   unsigned* __restrict__ cursors)
{
    int i = blockIdx.x * 256 + threadIdx.x;
    if (i < N_ATOMS) {
        unsigned base = row_start[i] + blksum[i >> 8];
        row_start[i] = base;
        cursors[i]   = base;
    }
    if (i == 0) row_start[N_ATOMS] = N_EDGES;
}

__global__ __launch_bounds__(256) void fill_csr(const int* __restrict__ eidx,
                                                unsigned* __restrict__ cursors,
                                                unsigned* __restrict__ csr)
{
    int e = blockIdx.x * 256 + threadIdx.x;
    int d = eidx[2 * e + 1];
    unsigned pos = atomicAdd(&cursors[d], 1u);
    csr[pos] = (unsigned)e;
}

// ---------------------------------------------------------------------------
// Pass 3: gather-reduce. One wave per atom, lane = column. Walk the atom's
// edge list (wave-uniform CSR reads -> scalar loads), read each edge's 256B
// packed pre-act row coalesced, accumulate in registers, one store per atom.
// No atomics.
// ---------------------------------------------------------------------------
__global__ __launch_bounds__(256) void bn_act_reduce(
    const unsigned* __restrict__ ws_pre, const unsigned* __restrict__ csr,
    const unsigned* __restrict__ row_start, const float* __restrict__ atom,
    const float* __restrict__ params, float* __restrict__ out)
{
    const int lane = threadIdx.x & 63;
    const int a    = blockIdx.x * 4 + (threadIdx.x >> 6);

    const float sc_c = params[lane],      sh_c = params[128 + lane];
    const float sc_f = params[64 + lane], sh_f = params[192 + lane];

    unsigned j   = row_start[a];
    unsigned end = row_start[a + 1];
    float acc = 0.f;

    for (; j + 4 <= end; j += 4) {
        unsigned e0 = csr[j], e1 = csr[j + 1], e2 = csr[j + 2], e3 = csr[j + 3];
        unsigned p0 = ws_pre[(size_t)e0 * 64 + lane];
        unsigned p1 = ws_pre[(size_t)e1 * 64 + lane];
        unsigned p2 = ws_pre[(size_t)e2 * 64 + lane];
        unsigned p3 = ws_pre[(size_t)e3 * 64 + lane];
        acc += msgf(p0, sc_c, sh_c, sc_f, sh_f);
        acc += msgf(p1, sc_c, sh_c, sc_f, sh_f);
        acc += msgf(p2, sc_c, sh_c, sc_f, sh_f);
        acc += msgf(p3, sc_c, sh_c, sc_f, sh_f);
    }
    for (; j < end; ++j) {
        unsigned e = csr[j];
        acc += msgf(ws_pre[(size_t)e * 64 + lane], sc_c, sh_c, sc_f, sh_f);
    }
    out[(size_t)a * 64 + lane] = atom[(size_t)a * 64 + lane] + acc;
}

// ---------------------------------------------------------------------------
// Fallback path (ws too small): recompute GEMM + atomic scatter.
// ---------------------------------------------------------------------------
__global__ __launch_bounds__(256) void copy_out(const f32x4* __restrict__ src,
                                                f32x4* __restrict__ dst)
{
    int i = blockIdx.x * blockDim.x + threadIdx.x;
    dst[i] = src[i];
}

__global__ __launch_bounds__(256) void apply_scatter_fb(
    const float* __restrict__ atom, const float* __restrict__ edgef,
    const ushort* __restrict__ Wb, const int* __restrict__ eidx,
    const float* __restrict__ params, float* __restrict__ out)
{
    __shared__ __align__(16) ushort zl[TILE_E * ZSTRIDE];
    __shared__ int eidxl[TPB * 128];
    const int tid  = threadIdx.x;
    const int lane = tid & 63, wave = tid >> 6;
    const int ch = wave >> 1, rp = wave & 1;
    const int row = lane & 15, quad = lane >> 4;

    const int base2 = blockIdx.x * TPB * 128;
    for (int i = tid; i < TPB * 128; i += 256) eidxl[i] = eidx[base2 + i];

    bf16x8 bfr[2][2][6];
#pragma unroll
    for (int m = 0; m < 2; ++m)
#pragma unroll
        for (int nt = 0; nt < 2; ++nt)
#pragma unroll
            for (int ks = 0; ks < 6; ++ks)
                bfr[m][nt][ks] = *(const bf16x8*)&Wb[
                    (size_t)(m * 64 + ch * 32 + nt * 16 + row) * KDIM + ks * 32 + quad * 8];

    float scc[2], shc[2], scf[2], shf[2];
#pragma unroll
    for (int nt = 0; nt < 2; ++nt) {
        int c = ch * 32 + nt * 16 + row;
        scc[nt] = params[c];        shc[nt] = params[128 + c];
        scf[nt] = params[64 + c];   shf[nt] = params[192 + c];
    }

    const int t0 = blockIdx.x * TPB;
    for (int tt = 0; tt < TPB; ++tt) {
        const int tilebase = (t0 + tt) * TILE_E;
        __syncthreads();
        gather_tile(atom, edgef, eidxl + tt * 128, tilebase, zl, tid);
        __syncthreads();
#pragma unroll
        for (int ett = 0; ett < 2; ++ett) {
            const ushort* zb = zl + ((2 * rp + ett) * 16 + row) * ZSTRIDE;
            bf16x8 a[6];
#pragma unroll
            for (int ks = 0; ks < 6; ++ks)
                a[ks] = *(const bf16x8*)&zb[ks * 32 + quad * 8];
            f32x4 acc[2][2];
#pragma unroll
            for (int m = 0; m < 2; ++m)
#pragma unroll
                for (int nt = 0; nt < 2; ++nt)
                    acc[m][nt] = (f32x4){0.f, 0.f, 0.f, 0.f};
#pragma unroll
            for (int ks = 0; ks < 6; ++ks)
#pragma unroll
                for (int m = 0; m < 2; ++m)
#pragma unroll
                    for (int nt = 0; nt < 2; ++nt)
                        acc[m][nt] = __builtin_amdgcn_mfma_f32_16x16x32_bf16(
                            a[ks], bfr[m][nt][ks], acc[m][nt], 0, 0, 0);
#pragma unroll
            for (int nt = 0; nt < 2; ++nt) {
                int c = ch * 32 + nt * 16 + row;
#pragma unroll
                for (int r = 0; r < 4; ++r) {
                    float pc = fmaf(acc[0][nt][r], scc[nt], shc[nt]);
                    float pf = fmaf(acc[1][nt][r], scf[nt], shf[nt]);
                    float sp = fmaxf(pc, 0.f) + __logf(1.f + __expf(-fabsf(pc)));
                    float sg = 1.f / (1.f + __expf(-pf));
                    int eloc = (2 * rp + ett) * 16 + quad * 4 + r;
                    int d = eidxl[tt * 128 + 2 * eloc + 1];
                    atomicAdd(out + (size_t)d * 64 + c, sp * sg);
                }
            }
        }
    }
}

// ---------------------------------------------------------------------------
extern "C" void kernel_launch(void* const* d_in, const int* in_sizes, int n_in,
                              void* d_out, int out_size, void* d_ws, size_t ws_size,
                              hipStream_t stream)
{
    const float* atom  = (const float*)d_in[0];
    const float* edgef = (const float*)d_in[1];
    const float* Wf    = (const float*)d_in[2];
    const float* gf    = (const float*)d_in[4];
    const float* btf   = (const float*)d_in[5];
    const float* Wc    = (const float*)d_in[6];
    const float* gc    = (const float*)d_in[8];
    const float* btc   = (const float*)d_in[9];
    const int*   eidx  = (const int*)d_in[10];
    float* out = (float*)d_out;

    // workspace layout (ws_pre first keeps everything 16B-aligned)
    unsigned* ws_pre       = (unsigned*)d_ws;                          // N_EDGES*64
    float*    stat_partial = (float*)(ws_pre + (size_t)N_EDGES * 64);  // 8192 f32
    float*    params       = stat_partial + STAT_SLOTS * 256;          // 256 f32
    ushort*   Wb           = (ushort*)(params + 256);                  // 24576 bf16
    unsigned* counts       = (unsigned*)(Wb + 2 * 64 * KDIM);          // 50000
    unsigned* row_start    = counts + N_ATOMS;                         // 50001
    unsigned* blksum       = row_start + N_ATOMS + 1;                  // 256
    unsigned* cursors      = blksum + 256;                             // 50000
    unsigned* csr          = cursors + N_ATOMS;                        // 800000

    const size_t need_full = (size_t)((char*)(csr + N_EDGES) - (char*)d_ws);
    const int full = (ws_size >= need_full) ? 1 : 0;

    (void)hipMemsetAsync(stat_partial, 0, STAT_SLOTS * 256 * sizeof(float), stream);
    convert_weights<<<(2 * 64 * KDIM) / 256, 256, 0, stream>>>(Wc, Wf, Wb);

    if (full) {
        (void)hipMemsetAsync(counts, 0, N_ATOMS * sizeof(unsigned), stream);
        hist_dst<<<N_EDGES / 256, 256, 0, stream>>>(eidx, counts);
        gemm_stats_store<<<GRID1, 256, 0, stream>>>(atom, edgef, Wb, eidx,
                                                    stat_partial, ws_pre, 1);
        finalize_stats<<<1, 128, 0, stream>>>(stat_partial, gc, btc, gf, btf, params);
        scan_a<<<NSCANBLK, 256, 0, stream>>>(counts, row_start, blksum);
        scan_b<<<1, 256, 0, stream>>>(blksum);
        init_cursor<<<NSCANBLK, 256, 0, stream>>>(row_start, blksum, cursors);
        fill_csr<<<N_EDGES / 256, 256, 0, stream>>>(eidx, cursors, csr);
        bn_act_reduce<<<N_ATOMS / 4, 256, 0, stream>>>(ws_pre, csr, row_start,
                                                       atom, params, out);
    } else {
        gemm_stats_store<<<GRID1, 256, 0, stream>>>(atom, edgef, Wb, eidx,
                                                    stat_partial, ws_pre, 0);
        finalize_stats<<<1, 128, 0, stream>>>(stat_partial, gc, btc, gf, btf, params);
        copy_out<<<(N_ATOMS * 64 / 4) / 256, 256, 0, stream>>>(
            (const f32x4*)atom, (f32x4*)out);
        apply_scatter_fb<<<GRID1, 256, 0, stream>>>(atom, edgef, Wb, eidx,
                                                    params, out);
    }
}

// Round 6
// 530.879 us; speedup vs baseline: 5.5045x; 1.0456x over previous
//
#include <hip/hip_runtime.h>
#include <hip/hip_bf16.h>
#include <math.h>

// Problem constants
#define N_ATOMS   50000
#define N_EDGES   800000
#define KDIM      192
#define BN_EPS    1e-5f

#define TILE_E     64
#define TPB        5                       // tiles per block (pass 1)
#define NTILES     (N_EDGES / TILE_E)      // 12500
#define GRID1      (NTILES / TPB)          // 2500
#define STAT_SLOTS 32
#define ZSTRIDE    200   // bf16 elems per z row (192 + 8 pad, 16B-aligned rows)
#define NSCANBLK   ((N_ATOMS + 255) / 256) // 196

typedef __attribute__((ext_vector_type(8))) __bf16 bf16x8;
typedef __attribute__((ext_vector_type(4))) float  f32x4;
typedef __attribute__((ext_vector_type(4))) unsigned short u16x4;

__device__ __forceinline__ ushort f2bf(float f) {
    union { float f; unsigned u; } v; v.f = f;
    unsigned u = v.u;
    return (ushort)((u + 0x7FFFu + ((u >> 16) & 1u)) >> 16);
}
__device__ __forceinline__ float bf2f(unsigned hi16) {
    union { unsigned u; float f; } v; v.u = hi16 << 16; return v.f;
}
// BN + sigmoid*softplus message from packed (core | filter<<16) bf16 pair
__device__ __forceinline__ float msgf(unsigned pv, float sc_c, float sh_c,
                                      float sc_f, float sh_f) {
    float pc = fmaf(bf2f(pv & 0xFFFFu), sc_c, sh_c);
    float pf = fmaf(bf2f(pv >> 16),     sc_f, sh_f);
    float sp = fmaxf(pc, 0.f) + __logf(1.f + __expf(-fabsf(pc)));
    float sg = 1.f / (1.f + __expf(-pf));
    return sp * sg;
}

// ---------------------------------------------------------------------------
// Gather split: issue (global loads -> regs) / commit (bf16 convert -> LDS).
// eidx is read directly from global (16 threads/edge share -> L1 broadcast).
// ---------------------------------------------------------------------------
__device__ __forceinline__ void gather_issue(
    const float* __restrict__ atom, const float* __restrict__ edgef,
    const int* __restrict__ eidx, int tilebase, int tid, f32x4* v)
{
    const int er = tid >> 4, f4 = tid & 15;
#pragma unroll
    for (int it = 0; it < 12; ++it) {
        const int seg = it >> 2;
        const int e   = (it & 3) * 16 + er;
        const float* srcp;
        if (seg == 0)      srcp = atom  + (size_t)eidx[2 * (tilebase + e) + 1] * 64;
        else if (seg == 1) srcp = atom  + (size_t)eidx[2 * (tilebase + e)] * 64;
        else               srcp = edgef + (size_t)(tilebase + e) * 64;
        v[it] = *(const f32x4*)(srcp + f4 * 4);
    }
}

__device__ __forceinline__ void gather_commit(const f32x4* v, ushort* zl, int tid)
{
    const int er = tid >> 4, f4 = tid & 15;
#pragma unroll
    for (int it = 0; it < 12; ++it) {
        const int seg = it >> 2;
        const int e   = (it & 3) * 16 + er;
        u16x4 b;
        b.x = f2bf(v[it].x); b.y = f2bf(v[it].y);
        b.z = f2bf(v[it].z); b.w = f2bf(v[it].w);
        *(u16x4*)&zl[e * ZSTRIDE + seg * 64 + f4 * 4] = b;
    }
}

// ---------------------------------------------------------------------------
// Pass 1: prefetch-double-buffered gather + MFMA dual-GEMM + column sum/sumsq.
// Pre-act rows stored PERMUTED to CSR slots (perm[e]) so the reduce pass
// streams sequentially. Bias dropped (cancels under BN).
// One __syncthreads per tile: commit(t) | sync | issue(t+1) | MFMA(t)+store.
// ---------------------------------------------------------------------------
__global__ __launch_bounds__(256) void gemm_stats_store(
    const float* __restrict__ atom, const float* __restrict__ edgef,
    const ushort* __restrict__ Wb, const int* __restrict__ eidx,
    const unsigned* __restrict__ perm,
    float* __restrict__ stat_partial, unsigned* __restrict__ ws_pre,
    int do_store)
{
    __shared__ __align__(16) ushort zbuf[2][TILE_E * ZSTRIDE]; // 2x25.6KB
    __shared__ unsigned perml[TPB * TILE_E];                   // 1.25KB
    const int tid  = threadIdx.x;
    const int lane = tid & 63, wave = tid >> 6;
    const int ch = wave >> 1, rp = wave & 1;
    const int row = lane & 15, quad = lane >> 4;

    const int t0 = blockIdx.x * TPB;
    for (int i = tid; i < TPB * TILE_E; i += 256)
        perml[i] = perm[t0 * TILE_E + i];

    bf16x8 bfr[2][2][6];
#pragma unroll
    for (int m = 0; m < 2; ++m)
#pragma unroll
        for (int nt = 0; nt < 2; ++nt)
#pragma unroll
            for (int ks = 0; ks < 6; ++ks)
                bfr[m][nt][ks] = *(const bf16x8*)&Wb[
                    (size_t)(m * 64 + ch * 32 + nt * 16 + row) * KDIM + ks * 32 + quad * 8];

    float s[2][2] = {{0.f, 0.f}, {0.f, 0.f}};
    float q[2][2] = {{0.f, 0.f}, {0.f, 0.f}};

    f32x4 pre[12];
    gather_issue(atom, edgef, eidx, t0 * TILE_E, tid, pre);

    for (int tt = 0; tt < TPB; ++tt) {
        ushort* zl = zbuf[tt & 1];
        gather_commit(pre, zl, tid);
        __syncthreads();   // zl visible; also protects buffer reuse (see R6 note)
        if (tt + 1 < TPB)
            gather_issue(atom, edgef, eidx, (t0 + tt + 1) * TILE_E, tid, pre);

#pragma unroll
        for (int ett = 0; ett < 2; ++ett) {
            const ushort* zb = zl + ((2 * rp + ett) * 16 + row) * ZSTRIDE;
            bf16x8 a[6];
#pragma unroll
            for (int ks = 0; ks < 6; ++ks)
                a[ks] = *(const bf16x8*)&zb[ks * 32 + quad * 8];
            f32x4 acc[2][2];
#pragma unroll
            for (int m = 0; m < 2; ++m)
#pragma unroll
                for (int nt = 0; nt < 2; ++nt)
                    acc[m][nt] = (f32x4){0.f, 0.f, 0.f, 0.f};
#pragma unroll
            for (int ks = 0; ks < 6; ++ks)
#pragma unroll
                for (int m = 0; m < 2; ++m)
#pragma unroll
                    for (int nt = 0; nt < 2; ++nt)
                        acc[m][nt] = __builtin_amdgcn_mfma_f32_16x16x32_bf16(
                            a[ks], bfr[m][nt][ks], acc[m][nt], 0, 0, 0);
#pragma unroll
            for (int nt = 0; nt < 2; ++nt) {
                const int c = ch * 32 + nt * 16 + row;
#pragma unroll
                for (int r = 0; r < 4; ++r) {
                    float vc = acc[0][nt][r], vf = acc[1][nt][r];
                    s[0][nt] += vc; q[0][nt] += vc * vc;
                    s[1][nt] += vf; q[1][nt] += vf * vf;
                    if (do_store) {
                        const int eloc = (2 * rp + ett) * 16 + quad * 4 + r;
                        const unsigned pos = perml[tt * TILE_E + eloc];
                        unsigned pack = (unsigned)f2bf(vc) | ((unsigned)f2bf(vf) << 16);
                        ws_pre[(size_t)pos * 64 + c] = pack;  // plain store: L2 merges
                    }
                }
            }
        }
    }

    float* slot = stat_partial + (size_t)(blockIdx.x & (STAT_SLOTS - 1)) * 256;
#pragma unroll
    for (int m = 0; m < 2; ++m)
#pragma unroll
        for (int nt = 0; nt < 2; ++nt) {
            float sv = s[m][nt], qv = q[m][nt];
            sv += __shfl_xor(sv, 16, 64); sv += __shfl_xor(sv, 32, 64);
            qv += __shfl_xor(qv, 16, 64); qv += __shfl_xor(qv, 32, 64);
            if (lane < 16) {
                int c = ch * 32 + nt * 16 + lane;
                atomicAdd(slot + m * 128 + c, sv);
                atomicAdd(slot + m * 128 + 64 + c, qv);
            }
        }
}

// ---------------------------------------------------------------------------
// Fold BN into per-column scale/shift.
// params: [0..63]=scale_c [64..127]=scale_f [128..191]=shift_c [192..255]=shift_f
// ---------------------------------------------------------------------------
__global__ void finalize_stats(const float* __restrict__ stat_partial,
                               const float* __restrict__ gc, const float* __restrict__ btc,
                               const float* __restrict__ gf, const float* __restrict__ btf,
                               float* __restrict__ params)
{
    int t = threadIdx.x;            // 0..127
    bool isf = t >= 64;
    int j = t & 63;
    float s = 0.f, q = 0.f;
    for (int slot = 0; slot < STAT_SLOTS; slot++) {
        const float* sp = stat_partial + (size_t)slot * 256 + (isf ? 128 : 0);
        s += sp[j];
        q += sp[64 + j];
    }
    float mean = s / (float)N_EDGES;
    float var  = q / (float)N_EDGES - mean * mean;
    float inv  = rsqrtf(var + BN_EPS);
    float gamma = isf ? gf[j] : gc[j];
    float beta  = isf ? btf[j] : btc[j];
    float scale = gamma * inv;
    float shift = beta - mean * scale;
    params[t]       = scale;
    params[128 + t] = shift;
}

__global__ __launch_bounds__(256) void convert_weights(
    const float* __restrict__ Wc, const float* __restrict__ Wf,
    ushort* __restrict__ Wb)
{
    int i = blockIdx.x * 256 + threadIdx.x;
    float v = (i < 64 * KDIM) ? Wc[i] : Wf[i - 64 * KDIM];
    Wb[i] = f2bf(v);
}

// ---------------------------------------------------------------------------
// CSR-slot assignment: histogram -> 2-level exclusive scan -> cursors ->
// perm[e] = slot (coalesced write; no scattered csr array).
// ---------------------------------------------------------------------------
__global__ __launch_bounds__(256) void hist_dst(const int* __restrict__ eidx,
                                                unsigned* __restrict__ counts)
{
    int e = blockIdx.x * 256 + threadIdx.x;          // 3125 blocks
    atomicAdd(&counts[eidx[2 * e + 1]], 1u);
}

__global__ __launch_bounds__(256) void scan_a(const unsigned* __restrict__ counts,
                                              unsigned* __restrict__ row_start,
                                              unsigned* __restrict__ blksum)
{
    __shared__ unsigned sh[256];
    const int tid = threadIdx.x;
    const int i = blockIdx.x * 256 + tid;
    unsigned v = (i < N_ATOMS) ? counts[i] : 0u;
    sh[tid] = v;
    __syncthreads();
    for (int off = 1; off < 256; off <<= 1) {
        unsigned t = (tid >= off) ? sh[tid - off] : 0u;
        __syncthreads();
        sh[tid] += t;
        __syncthreads();
    }
    if (i < N_ATOMS) row_start[i] = sh[tid] - v;     // exclusive
    if (tid == 255) blksum[blockIdx.x] = sh[tid];
}

__global__ void scan_b(unsigned* __restrict__ blksum)   // 1 block
{
    __shared__ unsigned sh[256];
    const int tid = threadIdx.x;
    unsigned v = (tid < NSCANBLK) ? blksum[tid] : 0u;
    sh[tid] = v;
    __syncthreads();
    for (int off = 1; off < 256; off <<= 1) {
        unsigned t = (tid >= off) ? sh[tid - off] : 0u;
        __syncthreads();
        sh[tid] += t;
        __syncthreads();
    }
    if (tid < NSCANBLK) blksum[tid] = sh[tid] - v;   // exclusive
}

__global__ __launch_bounds__(256) void init_cursor(unsigned* __restrict__ row_start,
                                                   const unsigned* __restrict__ blksum,
                                                   unsigned* __restrict__ cursors)
{
    int i = blockIdx.x * 256 + threadIdx.x;
    if (i < N_ATOMS) {
        unsigned base = row_start[i] + blksum[i >> 8];
        row_start[i] = base;
        cursors[i]   = base;
    }
    if (i == 0) row_start[N_ATOMS] = N_EDGES;
}

__global__ __launch_bounds__(256) void fill_perm(const int* __restrict__ eidx,
                                                 unsigned* __restrict__ cursors,
                                                 unsigned* __restrict__ perm)
{
    int e = blockIdx.x * 256 + threadIdx.x;
    int d = eidx[2 * e + 1];
    perm[e] = atomicAdd(&cursors[d], 1u);   // coalesced perm write
}

// ---------------------------------------------------------------------------
// Pass 3: streaming gather-reduce. ws_pre rows are already in CSR order, so
// each wave (one atom, lane = column) reads a CONTIGUOUS run of 256B rows.
// One plain store per atom; no atomics, no index indirection.
// ---------------------------------------------------------------------------
__global__ __launch_bounds__(256) void bn_act_reduce(
    const unsigned* __restrict__ ws_pre, const unsigned* __restrict__ row_start,
    const float* __restrict__ atom, const float* __restrict__ params,
    float* __restrict__ out)
{
    const int lane = threadIdx.x & 63;
    const int a    = blockIdx.x * 4 + (threadIdx.x >> 6);

    const float sc_c = params[lane],      sh_c = params[128 + lane];
    const float sc_f = params[64 + lane], sh_f = params[192 + lane];

    const unsigned jb = row_start[a];
    const unsigned n  = row_start[a + 1] - jb;
    const unsigned* base = ws_pre + (size_t)jb * 64 + lane;

    float acc = 0.f;
    unsigned k = 0;
    for (; k + 8 <= n; k += 8) {
        unsigned p[8];
#pragma unroll
        for (int u = 0; u < 8; ++u) p[u] = base[(size_t)(k + u) * 64];
#pragma unroll
        for (int u = 0; u < 8; ++u) acc += msgf(p[u], sc_c, sh_c, sc_f, sh_f);
    }
    for (; k < n; ++k) acc += msgf(base[(size_t)k * 64], sc_c, sh_c, sc_f, sh_f);

    out[(size_t)a * 64 + lane] = atom[(size_t)a * 64 + lane] + acc;
}

// ---------------------------------------------------------------------------
// Fallback path (ws too small): recompute GEMM + atomic scatter (no ws_pre).
// ---------------------------------------------------------------------------
__global__ __launch_bounds__(256) void copy_out(const f32x4* __restrict__ src,
                                                f32x4* __restrict__ dst)
{
    int i = blockIdx.x * blockDim.x + threadIdx.x;
    dst[i] = src[i];
}

__global__ __launch_bounds__(256) void apply_scatter_fb(
    const float* __restrict__ atom, const float* __restrict__ edgef,
    const ushort* __restrict__ Wb, const int* __restrict__ eidx,
    const float* __restrict__ params, float* __restrict__ out)
{
    __shared__ __align__(16) ushort zl[TILE_E * ZSTRIDE];
    const int tid  = threadIdx.x;
    const int lane = tid & 63, wave = tid >> 6;
    const int ch = wave >> 1, rp = wave & 1;
    const int row = lane & 15, quad = lane >> 4;

    bf16x8 bfr[2][2][6];
#pragma unroll
    for (int m = 0; m < 2; ++m)
#pragma unroll
        for (int nt = 0; nt < 2; ++nt)
#pragma unroll
            for (int ks = 0; ks < 6; ++ks)
                bfr[m][nt][ks] = *(const bf16x8*)&Wb[
                    (size_t)(m * 64 + ch * 32 + nt * 16 + row) * KDIM + ks * 32 + quad * 8];

    float scc[2], shc[2], scf[2], shf[2];
#pragma unroll
    for (int nt = 0; nt < 2; ++nt) {
        int c = ch * 32 + nt * 16 + row;
        scc[nt] = params[c];        shc[nt] = params[128 + c];
        scf[nt] = params[64 + c];   shf[nt] = params[192 + c];
    }

    const int t0 = blockIdx.x * TPB;
    for (int tt = 0; tt < TPB; ++tt) {
        const int tilebase = (t0 + tt) * TILE_E;
        f32x4 pre[12];
        gather_issue(atom, edgef, eidx, tilebase, tid, pre);
        __syncthreads();
        gather_commit(pre, zl, tid);
        __syncthreads();
#pragma unroll
        for (int ett = 0; ett < 2; ++ett) {
            const ushort* zb = zl + ((2 * rp + ett) * 16 + row) * ZSTRIDE;
            bf16x8 a[6];
#pragma unroll
            for (int ks = 0; ks < 6; ++ks)
                a[ks] = *(const bf16x8*)&zb[ks * 32 + quad * 8];
            f32x4 acc[2][2];
#pragma unroll
            for (int m = 0; m < 2; ++m)
#pragma unroll
                for (int nt = 0; nt < 2; ++nt)
                    acc[m][nt] = (f32x4){0.f, 0.f, 0.f, 0.f};
#pragma unroll
            for (int ks = 0; ks < 6; ++ks)
#pragma unroll
                for (int m = 0; m < 2; ++m)
#pragma unroll
                    for (int nt = 0; nt < 2; ++nt)
                        acc[m][nt] = __builtin_amdgcn_mfma_f32_16x16x32_bf16(
                            a[ks], bfr[m][nt][ks], acc[m][nt], 0, 0, 0);
#pragma unroll
            for (int nt = 0; nt < 2; ++nt) {
                int c = ch * 32 + nt * 16 + row;
#pragma unroll
                for (int r = 0; r < 4; ++r) {
                    float pc = fmaf(acc[0][nt][r], scc[nt], shc[nt]);
                    float pf = fmaf(acc[1][nt][r], scf[nt], shf[nt]);
                    float sp = fmaxf(pc, 0.f) + __logf(1.f + __expf(-fabsf(pc)));
                    float sg = 1.f / (1.f + __expf(-pf));
                    int eloc = (2 * rp + ett) * 16 + quad * 4 + r;
                    int d = eidx[2 * (tilebase + eloc) + 1];
                    atomicAdd(out + (size_t)d * 64 + c, sp * sg);
                }
            }
        }
    }
}

// ---------------------------------------------------------------------------
extern "C" void kernel_launch(void* const* d_in, const int* in_sizes, int n_in,
                              void* d_out, int out_size, void* d_ws, size_t ws_size,
                              hipStream_t stream)
{
    const float* atom  = (const float*)d_in[0];
    const float* edgef = (const float*)d_in[1];
    const float* Wf    = (const float*)d_in[2];
    const float* gf    = (const float*)d_in[4];
    const float* btf   = (const float*)d_in[5];
    const float* Wc    = (const float*)d_in[6];
    const float* gc    = (const float*)d_in[8];
    const float* btc   = (const float*)d_in[9];
    const int*   eidx  = (const int*)d_in[10];
    float* out = (float*)d_out;

    // workspace layout (ws_pre first keeps everything 16B-aligned)
    unsigned* ws_pre       = (unsigned*)d_ws;                          // N_EDGES*64
    float*    stat_partial = (float*)(ws_pre + (size_t)N_EDGES * 64);  // 8192 f32
    float*    params       = stat_partial + STAT_SLOTS * 256;          // 256 f32
    ushort*   Wb           = (ushort*)(params + 256);                  // 24576 bf16
    unsigned* counts       = (unsigned*)(Wb + 2 * 64 * KDIM);          // 50000
    unsigned* row_start    = counts + N_ATOMS;                         // 50001
    unsigned* blksum       = row_start + N_ATOMS + 1;                  // 256
    unsigned* cursors      = blksum + 256;                             // 50000
    unsigned* perm         = cursors + N_ATOMS;                        // 800000

    const size_t need_full = (size_t)((char*)(perm + N_EDGES) - (char*)d_ws);
    const int full = (ws_size >= need_full) ? 1 : 0;

    (void)hipMemsetAsync(stat_partial, 0, STAT_SLOTS * 256 * sizeof(float), stream);
    convert_weights<<<(2 * 64 * KDIM) / 256, 256, 0, stream>>>(Wc, Wf, Wb);

    if (full) {
        (void)hipMemsetAsync(counts, 0, N_ATOMS * sizeof(unsigned), stream);
        hist_dst<<<N_EDGES / 256, 256, 0, stream>>>(eidx, counts);
        scan_a<<<NSCANBLK, 256, 0, stream>>>(counts, row_start, blksum);
        scan_b<<<1, 256, 0, stream>>>(blksum);
        init_cursor<<<NSCANBLK, 256, 0, stream>>>(row_start, blksum, cursors);
        fill_perm<<<N_EDGES / 256, 256, 0, stream>>>(eidx, cursors, perm);
        gemm_stats_store<<<GRID1, 256, 0, stream>>>(atom, edgef, Wb, eidx, perm,
                                                    stat_partial, ws_pre, 1);
        finalize_stats<<<1, 128, 0, stream>>>(stat_partial, gc, btc, gf, btf, params);
        bn_act_reduce<<<N_ATOMS / 4, 256, 0, stream>>>(ws_pre, row_start,
                                                       atom, params, out);
    } else {
        gemm_stats_store<<<GRID1, 256, 0, stream>>>(atom, edgef, Wb, eidx,
                                                    (unsigned*)counts /*unused*/,
                                                    stat_partial, ws_pre, 0);
        finalize_stats<<<1, 128, 0, stream>>>(stat_partial, gc, btc, gf, btf, params);
        copy_out<<<(N_ATOMS * 64 / 4) / 256, 256, 0, stream>>>(
            (const f32x4*)atom, (f32x4*)out);
        apply_scatter_fb<<<GRID1, 256, 0, stream>>>(atom, edgef, Wb, eidx,
                                                    params, out);
    }
}